// Round 4
// baseline (137.039 us; speedup 1.0000x reference)
//
#include <hip/hip_runtime.h>

// Problem constants (x: [3, 64, 64] float32)
#define C_DIM   3
#define H_DIM   64
#define W_DIM   64
#define HW      (H_DIM * W_DIM)          // 4096
#define N_TOT   (C_DIM * HW)             // 12288
#define PREP_T  1024
#define PER     (N_TOT / PREP_T)         // 12
#define FILL_T  256
#define F4_PER_ROW (N_TOT / 4)           // 3072
#define F4_PER_THR (F4_PER_ROW / FILL_T) // 12
#define EPS_F   0.1f

typedef float f4 __attribute__((ext_vector_type(4)));

// Workspace layout (floats/ints, all 4B):
//   center : N_TOT floats            (ws + 0)
//   errmap : N_TOT+1 floats          (ws + N_TOT)
//   colmap : N_TOT+1 ints            (ws + 2*N_TOT + 1)

// Prep: compute center/err, block-wide scan of mask -> 1-based rows,
// build inverse map (row -> col, err), write terms.
__global__ __launch_bounds__(PREP_T) void zono_prep(
        const float* __restrict__ x,
        float* __restrict__ terms,     // N x 2 as float32
        float* __restrict__ center,
        float* __restrict__ errmap,
        int*   __restrict__ colmap)
{
    const int tid  = threadIdx.x;
    const int base = tid * PER;

    float cen[PER];
    float ev[PER];
    bool  m[PER];
    int   cnt = 0;

#pragma unroll
    for (int i = 0; i < PER; ++i) {
        float xv = x[base + i];
        float a  = fmaxf(EPS_F - xv, 0.0f) * 0.5f;
        float b  = fmaxf(xv - (1.0f - EPS_F), 0.0f) * 0.5f;
        cen[i]   = xv + a - b;
        float e  = EPS_F - a - b;
        ev[i]    = e;
        m[i]     = (e >= 0.0f);
        cnt     += m[i] ? 1 : 0;
        center[base + i] = cen[i];
        colmap[base + i + 1] = -1;     // default: row has no nonzero
    }

    // Block-wide inclusive scan (Hillis-Steele) over per-thread mask counts.
    __shared__ int sh[PREP_T];
    sh[tid] = cnt;
    __syncthreads();
    for (int off = 1; off < PREP_T; off <<= 1) {
        int t = (tid >= off) ? sh[tid - off] : 0;
        __syncthreads();
        sh[tid] += t;
        __syncthreads();
    }
    int run = sh[tid] - cnt;  // exclusive prefix for this thread's chunk
    // (colmap default writes above are ordered before these scatters by
    //  the scan's __syncthreads barriers)

#pragma unroll
    for (int i = 0; i < PER; ++i) {
        const int idx = base + i;
        float rowf, fidxf;
        if (m[i]) {
            ++run;                      // 1-based cumsum value
            colmap[run] = idx;
            errmap[run] = ev[i];
            rowf  = (float)run;
            fidxf = (float)(idx / HW);
        } else {
            rowf  = -1.0f;
            fidxf = -1.0f;
        }
        terms[2 * idx + 0] = rowf;
        terms[2 * idx + 1] = fidxf;
    }
}

// Fill: one workgroup per output row; plain float4 streaming stores.
// No runtime vector indexing (rule #20): component-wise selects only.
__global__ __launch_bounds__(FILL_T) void zono_fill(
        float* __restrict__ zono,
        const float* __restrict__ center,
        const float* __restrict__ errmap,
        const int*   __restrict__ colmap)
{
    const int row = blockIdx.x;
    f4* __restrict__ dst = (f4*)(zono + (size_t)row * N_TOT);

    if (row == 0) {
        const f4* __restrict__ src = (const f4*)center;
#pragma unroll
        for (int k = 0; k < F4_PER_THR; ++k) {
            int j = threadIdx.x + k * FILL_T;
            dst[j] = src[j];
        }
    } else {
        const int   col = colmap[row];          // -1 if row empty (never matches)
        const float ev  = errmap[row];
#pragma unroll
        for (int k = 0; k < F4_PER_THR; ++k) {
            int j  = threadIdx.x + k * FILL_T;
            int e0 = j << 2;
            f4 v;
            v.x = (e0 + 0 == col) ? ev : 0.0f;
            v.y = (e0 + 1 == col) ? ev : 0.0f;
            v.z = (e0 + 2 == col) ? ev : 0.0f;
            v.w = (e0 + 3 == col) ? ev : 0.0f;
            dst[j] = v;
        }
    }
}

extern "C" void kernel_launch(void* const* d_in, const int* in_sizes, int n_in,
                              void* d_out, int out_size, void* d_ws, size_t ws_size,
                              hipStream_t stream) {
    const float* x = (const float*)d_in[0];
    float* out = (float*)d_out;

    const size_t zono_elems = (size_t)(N_TOT + 1) * (size_t)N_TOT;  // 151,007,232
    float* terms = out + zono_elems;

    float* center = (float*)d_ws;
    float* errmap = center + N_TOT;
    int*   colmap = (int*)(errmap + N_TOT + 1);

    zono_prep<<<1, PREP_T, 0, stream>>>(x, terms, center, errmap, colmap);
    zono_fill<<<N_TOT + 1, FILL_T, 0, stream>>>(out, center, errmap, colmap);
}

// Round 5
// 134.237 us; speedup vs baseline: 1.0209x; 1.0209x over previous
//
#include <hip/hip_runtime.h>

// Problem constants (x: [3, 64, 64] float32)
#define C_DIM   3
#define H_DIM   64
#define W_DIM   64
#define HW      (H_DIM * W_DIM)          // 4096
#define N_TOT   (C_DIM * HW)             // 12288
#define PREP_T  1024
#define PER     (N_TOT / PREP_T)         // 12
#define FILL_T  256
#define FILL_B  2048
#define F4_PER_ROW (N_TOT / 4)           // 3072
#define EPS_F   0.1f

typedef float f4 __attribute__((ext_vector_type(4)));

// Workspace layout (floats/ints, all 4B):
//   errmap : N_TOT+1 floats          (ws + 0)
//   colmap : N_TOT+1 ints            (ws + N_TOT + 1)

// Prep: compute center/err, block-wide scan of mask -> 1-based rows,
// build inverse map (row -> col, err), write terms AND zono row 0 (center).
__global__ __launch_bounds__(PREP_T) void zono_prep(
        const float* __restrict__ x,
        float* __restrict__ zono_row0,   // zono row 0 (N_TOT floats)
        float* __restrict__ terms,       // N x 2 as float32
        float* __restrict__ errmap,
        int*   __restrict__ colmap)
{
    const int tid  = threadIdx.x;
    const int base = tid * PER;

    float ev[PER];
    bool  m[PER];
    int   cnt = 0;

#pragma unroll
    for (int i = 0; i < PER; ++i) {
        float xv = x[base + i];
        float a  = fmaxf(EPS_F - xv, 0.0f) * 0.5f;
        float b  = fmaxf(xv - (1.0f - EPS_F), 0.0f) * 0.5f;
        zono_row0[base + i] = xv + a - b;   // center
        float e  = EPS_F - a - b;
        ev[i]    = e;
        m[i]     = (e >= 0.0f);
        cnt     += m[i] ? 1 : 0;
        colmap[base + i + 1] = -1;          // default: row empty
    }

    // Block-wide inclusive scan (Hillis-Steele) over per-thread mask counts.
    __shared__ int sh[PREP_T];
    sh[tid] = cnt;
    __syncthreads();
    for (int off = 1; off < PREP_T; off <<= 1) {
        int t = (tid >= off) ? sh[tid - off] : 0;
        __syncthreads();
        sh[tid] += t;
        __syncthreads();
    }
    int run = sh[tid] - cnt;  // exclusive prefix for this thread's chunk
    // (colmap default writes above are ordered before these scatters by
    //  the scan's __syncthreads barriers)

#pragma unroll
    for (int i = 0; i < PER; ++i) {
        const int idx = base + i;
        float rowf, fidxf;
        if (m[i]) {
            ++run;                      // 1-based cumsum value
            colmap[run] = idx;
            errmap[run] = ev[i];
            rowf  = (float)run;
            fidxf = (float)(idx / HW);
        } else {
            rowf  = -1.0f;
            fidxf = -1.0f;
        }
        terms[2 * idx + 0] = rowf;
        terms[2 * idx + 1] = fidxf;
    }
}

// Fill rows 1..N with a FLAT grid-stride pattern (compact marching window,
// like rocclr fillBuffer) patching the one nonzero per row inline.
__global__ __launch_bounds__(FILL_T) void zono_fill(
        f4* __restrict__ zono4,          // full zono as f4[]
        const float* __restrict__ errmap,
        const int*   __restrict__ colmap)
{
    const unsigned total  = (unsigned)N_TOT * F4_PER_ROW;  // chunks in rows 1..N
    const unsigned stride = FILL_B * FILL_T;
    unsigned j = blockIdx.x * FILL_T + threadIdx.x;

    for (; j < total; j += stride) {
        unsigned row  = 1u + j / F4_PER_ROW;             // magic-mul div
        unsigned col0 = (j - (row - 1u) * F4_PER_ROW) << 2;
        int   col = colmap[row];                         // L1/L2-hot, -1 if empty
        float ev  = errmap[row];
        f4 v;
        v.x = ((int)(col0 + 0u) == col) ? ev : 0.0f;
        v.y = ((int)(col0 + 1u) == col) ? ev : 0.0f;
        v.z = ((int)(col0 + 2u) == col) ? ev : 0.0f;
        v.w = ((int)(col0 + 3u) == col) ? ev : 0.0f;
        zono4[F4_PER_ROW + j] = v;                       // skip row 0
    }
}

extern "C" void kernel_launch(void* const* d_in, const int* in_sizes, int n_in,
                              void* d_out, int out_size, void* d_ws, size_t ws_size,
                              hipStream_t stream) {
    const float* x = (const float*)d_in[0];
    float* out = (float*)d_out;

    const size_t zono_elems = (size_t)(N_TOT + 1) * (size_t)N_TOT;  // 151,007,232
    float* terms = out + zono_elems;

    float* errmap = (float*)d_ws;
    int*   colmap = (int*)(errmap + N_TOT + 1);

    zono_prep<<<1, PREP_T, 0, stream>>>(x, out, terms, errmap, colmap);
    zono_fill<<<FILL_B, FILL_T, 0, stream>>>((f4*)out, errmap, colmap);
}

// Round 6
// 123.041 us; speedup vs baseline: 1.1138x; 1.0910x over previous
//
#include <hip/hip_runtime.h>

// Problem constants (x: [3, 64, 64] float32)
#define C_DIM   3
#define H_DIM   64
#define W_DIM   64
#define HW      (H_DIM * W_DIM)          // 4096
#define N_TOT   (C_DIM * HW)             // 12288
#define PREP_T  1024
#define PER     (N_TOT / PREP_T)         // 12
#define PATCH_T 256
#define PATCH_B ((N_TOT + PATCH_T - 1) / PATCH_T)   // 48
#define EPS_F   0.1f

// Workspace layout (floats/ints, all 4B):
//   errmap : N_TOT+1 floats          (ws + 0)
//   colmap : N_TOT+1 ints            (ws + N_TOT + 1)

// Prep (single block): compute center/err, block-wide scan of mask ->
// 1-based rows, build inverse map (row -> col, err), write terms + row 0.
// Runs AFTER the memset (memset zeroes row 0 too).
__global__ __launch_bounds__(PREP_T) void zono_prep(
        const float* __restrict__ x,
        float* __restrict__ zono_row0,   // zono row 0 (N_TOT floats)
        float* __restrict__ terms,       // N x 2 as float32
        float* __restrict__ errmap,
        int*   __restrict__ colmap)
{
    const int tid  = threadIdx.x;
    const int base = tid * PER;

    float ev[PER];
    bool  m[PER];
    int   cnt = 0;

#pragma unroll
    for (int i = 0; i < PER; ++i) {
        float xv = x[base + i];
        float a  = fmaxf(EPS_F - xv, 0.0f) * 0.5f;
        float b  = fmaxf(xv - (1.0f - EPS_F), 0.0f) * 0.5f;
        zono_row0[base + i] = xv + a - b;   // center
        float e  = EPS_F - a - b;
        ev[i]    = e;
        m[i]     = (e >= 0.0f);
        cnt     += m[i] ? 1 : 0;
        colmap[base + i + 1] = -1;          // default: row empty
    }

    // Block-wide inclusive scan (Hillis-Steele) over per-thread mask counts.
    __shared__ int sh[PREP_T];
    sh[tid] = cnt;
    __syncthreads();
    for (int off = 1; off < PREP_T; off <<= 1) {
        int t = (tid >= off) ? sh[tid - off] : 0;
        __syncthreads();
        sh[tid] += t;
        __syncthreads();
    }
    int run = sh[tid] - cnt;  // exclusive prefix for this thread's chunk
    // (colmap default writes above are ordered before these scatters by
    //  the scan's __syncthreads barriers)

#pragma unroll
    for (int i = 0; i < PER; ++i) {
        const int idx = base + i;
        float rowf, fidxf;
        if (m[i]) {
            ++run;                      // 1-based cumsum value
            colmap[run] = idx;
            errmap[run] = ev[i];
            rowf  = (float)run;
            fidxf = (float)(idx / HW);
        } else {
            rowf  = -1.0f;
            fidxf = -1.0f;
        }
        terms[2 * idx + 0] = rowf;
        terms[2 * idx + 1] = fidxf;
    }
}

// Patch (multi-block): one thread per row r in 1..N; scattered 4B store of
// the row's single nonzero. 48 blocks spread the scattered-line latency
// across 48 CUs instead of 1 (R0's serial tail).
__global__ __launch_bounds__(PATCH_T) void zono_patch(
        float* __restrict__ zono,
        const float* __restrict__ errmap,
        const int*   __restrict__ colmap)
{
    const int r = 1 + blockIdx.x * PATCH_T + threadIdx.x;
    if (r > N_TOT) return;
    const int col = colmap[r];
    if (col >= 0) {
        zono[(size_t)r * N_TOT + col] = errmap[r];
    }
}

extern "C" void kernel_launch(void* const* d_in, const int* in_sizes, int n_in,
                              void* d_out, int out_size, void* d_ws, size_t ws_size,
                              hipStream_t stream) {
    const float* x = (const float*)d_in[0];
    float* out = (float*)d_out;

    const size_t zono_elems = (size_t)(N_TOT + 1) * (size_t)N_TOT;  // 151,007,232
    float* terms = out + zono_elems;

    float* errmap = (float*)d_ws;
    int*   colmap = (int*)(errmap + N_TOT + 1);

    // 1) Zero the full zonotope matrix (604 MB, runs at 82-86% write peak).
    hipMemsetAsync(out, 0, zono_elems * sizeof(float), stream);
    // 2) Single-block prep: scan + maps + terms + center row.
    zono_prep<<<1, PREP_T, 0, stream>>>(x, out, terms, errmap, colmap);
    // 3) Multi-block patch: scattered single-element stores.
    zono_patch<<<PATCH_B, PATCH_T, 0, stream>>>(out, errmap, colmap);
}